// Round 3
// baseline (409.092 us; speedup 1.0000x reference)
//
#include <hip/hip_runtime.h>
#include <math.h>

// Bahdanau attention, B=32, T=2048, D=512, U=512, fp32 in/out.
// Round 3: LDS-free MFMA GEMM. B = W1 pre-transposed+converted to f16 in ws
// (fragments load directly from global as 16B vectors, L2-resident); A
// fragments load as 2x float4 from values and convert in registers. No
// __syncthreads in the K-loop -> compiler pipelines loads across MFMAs.
// Fallback to the round-2 LDS kernel if ws_size < 832KB.

#define B_ 32
#define T_ 2048
#define D_ 512
#define U_ 512
#define M_ (B_ * T_)

typedef _Float16 half8 __attribute__((ext_vector_type(8)));
typedef float floatx4 __attribute__((ext_vector_type(4)));

__device__ __forceinline__ float fast_tanh(float x) {
  x = fminf(fmaxf(x, -20.f), 20.f);
  const float e = __expf(2.f * x);
  return 1.f - 2.f / (e + 1.f);
}

// ---------------- proj_q = query @ W2 + b2 ----------------
__global__ __launch_bounds__(256) void projq_kernel(
    const float* __restrict__ query, const float* __restrict__ W2,
    const float* __restrict__ b2, float* __restrict__ projq) {
  const int b = blockIdx.x;
  const int u = blockIdx.y * 256 + threadIdx.x;
  __shared__ float q[D_];
  for (int d = threadIdx.x; d < D_; d += 256) q[d] = query[b * D_ + d];
  __syncthreads();
  float acc = 0.f;
#pragma unroll 8
  for (int d = 0; d < D_; ++d) acc += q[d] * W2[d * U_ + u];
  projq[b * U_ + u] = acc + b2[u];
}

// ---------------- W1 [k][u] -> w1t [u][k] f16 ----------------
__global__ __launch_bounds__(256) void prep_w1t(
    const float* __restrict__ W1, _Float16* __restrict__ w1t) {
  __shared__ float t[64][65];
  const int k0 = blockIdx.x * 64, u0 = blockIdx.y * 64;
  const int lu = threadIdx.x & 63;
  const int g = threadIdx.x >> 6;
#pragma unroll
  for (int i = 0; i < 16; ++i) {
    const int row = g * 16 + i;
    t[row][lu] = W1[(long)(k0 + row) * U_ + u0 + lu];
  }
  __syncthreads();
#pragma unroll
  for (int i = 0; i < 16; ++i) {
    const int row = g * 16 + i;
    w1t[(long)(u0 + row) * D_ + k0 + lu] = (_Float16)t[lu][row];
  }
}

// ---------------- scores: LDS-free f16 MFMA GEMM + tanh/V epilogue --------
// Tile 128(M) x 128(U), 4 waves in 2x2 (wave = 64x64 via 4x4 16x16x32 MFMA).
// Frag layouts (verified): A[m=lane&15][k=(lane>>4)*8+j],
// B[k=(lane>>4)*8+j][n=lane&15], C[row=(lane>>4)*4+reg][col=lane&15].
__global__ __launch_bounds__(256) void score_direct_kernel(
    const float* __restrict__ values, const _Float16* __restrict__ w1t,
    const float* __restrict__ b1, const float* __restrict__ projq,
    const float* __restrict__ V, float* __restrict__ scores) {
  const int m0 = blockIdx.x * 128;
  const int u0 = blockIdx.y * 128;
  const int b = blockIdx.x >> 4;  // 2048/128 = 16 row-blocks per batch
  const int tid = threadIdx.x;
  const int lane = tid & 63;
  const int w = tid >> 6;
  const int wm = (w & 1) * 64;
  const int wn = (w >> 1) * 64;
  const int ln = lane & 15;
  const int lq = lane >> 4;

  const float* aBase = values + (long)(m0 + wm + ln) * D_ + lq * 8;
  const _Float16* bBase = w1t + (long)(u0 + wn + ln) * D_ + lq * 8;

  floatx4 acc[4][4] = {};

  for (int k0 = 0; k0 < D_; k0 += 32) {
    half8 af[4];
#pragma unroll
    for (int mi = 0; mi < 4; ++mi) {
      const float* p = aBase + (long)mi * 16 * D_ + k0;
      const float4 x = *(const float4*)p;
      const float4 y = *(const float4*)(p + 4);
      af[mi] = half8{(_Float16)x.x, (_Float16)x.y, (_Float16)x.z, (_Float16)x.w,
                     (_Float16)y.x, (_Float16)y.y, (_Float16)y.z, (_Float16)y.w};
    }
    half8 bf[4];
#pragma unroll
    for (int ni = 0; ni < 4; ++ni)
      bf[ni] = *(const half8*)(bBase + (long)ni * 16 * D_ + k0);
#pragma unroll
    for (int mi = 0; mi < 4; ++mi)
#pragma unroll
      for (int ni = 0; ni < 4; ++ni)
        acc[mi][ni] = __builtin_amdgcn_mfma_f32_16x16x32_f16(
            af[mi], bf[ni], acc[mi][ni], 0, 0, 0);
  }

  // Epilogue: s[row] += sum_col tanh(c + b1[u] + projq[b,u]) * V[u]
  float pre[4], vv[4];
#pragma unroll
  for (int ni = 0; ni < 4; ++ni) {
    const int u = u0 + wn + ni * 16 + ln;
    pre[ni] = b1[u] + projq[b * U_ + u];
    vv[ni] = V[u];
  }
#pragma unroll
  for (int mi = 0; mi < 4; ++mi) {
#pragma unroll
    for (int r = 0; r < 4; ++r) {
      float t = 0.f;
#pragma unroll
      for (int ni = 0; ni < 4; ++ni)
        t += fast_tanh(acc[mi][ni][r] + pre[ni]) * vv[ni];
      t += __shfl_xor(t, 1);
      t += __shfl_xor(t, 2);
      t += __shfl_xor(t, 4);
      t += __shfl_xor(t, 8);
      if (ln == mi * 4 + r)  // one atomic per lane
        atomicAdd(scores + m0 + wm + mi * 16 + lq * 4 + r, t);
    }
  }
}

// ---------------- round-2 LDS kernel: fallback if ws too small ------------
__global__ __launch_bounds__(256) void score_mfma_kernel(
    const float* __restrict__ values, const float* __restrict__ W1,
    const float* __restrict__ b1, const float* __restrict__ projq,
    const float* __restrict__ V, float* __restrict__ scores) {
  const int m0 = blockIdx.x * 128;
  const int u0 = blockIdx.y * 128;
  const int b = blockIdx.x >> 4;
  const int tid = threadIdx.x;
  __shared__ alignas(16) _Float16 As[128 * 32];
  __shared__ alignas(16) _Float16 Bs[128 * 32];
  const int lane = tid & 63;
  const int w = tid >> 6;
  const int wm = (w & 1) * 64;
  const int wn = (w >> 1) * 64;
  const int ln = lane & 15;
  const int lq = lane >> 4;
  floatx4 acc[4][4] = {};
  const int srow = tid >> 1;
  const int skoff = (tid & 1) * 16;
  const float* aptr = values + (long)(m0 + srow) * D_ + skoff;
  const float* bptr = W1 + u0 + srow;
  for (int k0 = 0; k0 < D_; k0 += 32) {
    const float4 a0 = *(const float4*)(aptr + k0);
    const float4 a1 = *(const float4*)(aptr + k0 + 4);
    const float4 a2 = *(const float4*)(aptr + k0 + 8);
    const float4 a3 = *(const float4*)(aptr + k0 + 12);
    half8 ha0 = {(_Float16)a0.x, (_Float16)a0.y, (_Float16)a0.z, (_Float16)a0.w,
                 (_Float16)a1.x, (_Float16)a1.y, (_Float16)a1.z, (_Float16)a1.w};
    half8 ha1 = {(_Float16)a2.x, (_Float16)a2.y, (_Float16)a2.z, (_Float16)a2.w,
                 (_Float16)a3.x, (_Float16)a3.y, (_Float16)a3.z, (_Float16)a3.w};
    float bt[16];
#pragma unroll
    for (int kk = 0; kk < 16; ++kk)
      bt[kk] = bptr[(long)(k0 + skoff + kk) * U_];
    half8 hb0 = {(_Float16)bt[0], (_Float16)bt[1], (_Float16)bt[2], (_Float16)bt[3],
                 (_Float16)bt[4], (_Float16)bt[5], (_Float16)bt[6], (_Float16)bt[7]};
    half8 hb1 = {(_Float16)bt[8], (_Float16)bt[9], (_Float16)bt[10], (_Float16)bt[11],
                 (_Float16)bt[12], (_Float16)bt[13], (_Float16)bt[14], (_Float16)bt[15]};
    *(half8*)&As[srow * 32 + skoff] = ha0;
    *(half8*)&As[srow * 32 + skoff + 8] = ha1;
    *(half8*)&Bs[srow * 32 + skoff] = hb0;
    *(half8*)&Bs[srow * 32 + skoff + 8] = hb1;
    __syncthreads();
    half8 af[4], bf[4];
#pragma unroll
    for (int i = 0; i < 4; ++i) {
      af[i] = *(const half8*)&As[(wm + i * 16 + ln) * 32 + lq * 8];
      bf[i] = *(const half8*)&Bs[(wn + i * 16 + ln) * 32 + lq * 8];
    }
#pragma unroll
    for (int mi = 0; mi < 4; ++mi)
#pragma unroll
      for (int ni = 0; ni < 4; ++ni)
        acc[mi][ni] = __builtin_amdgcn_mfma_f32_16x16x32_f16(
            af[mi], bf[ni], acc[mi][ni], 0, 0, 0);
    __syncthreads();
  }
  float pre[4], vv[4];
#pragma unroll
  for (int ni = 0; ni < 4; ++ni) {
    const int u = u0 + wn + ni * 16 + ln;
    pre[ni] = b1[u] + projq[b * U_ + u];
    vv[ni] = V[u];
  }
#pragma unroll
  for (int mi = 0; mi < 4; ++mi) {
#pragma unroll
    for (int r = 0; r < 4; ++r) {
      float t = 0.f;
#pragma unroll
      for (int ni = 0; ni < 4; ++ni)
        t += fast_tanh(acc[mi][ni][r] + pre[ni]) * vv[ni];
      t += __shfl_xor(t, 1);
      t += __shfl_xor(t, 2);
      t += __shfl_xor(t, 4);
      t += __shfl_xor(t, 8);
      if (ln == mi * 4 + r)
        atomicAdd(scores + m0 + wm + mi * 16 + lq * 4 + r, t);
    }
  }
}

// ---------------- softmax over T per batch ----------------
__global__ __launch_bounds__(256) void softmax_kernel(
    const float* __restrict__ scores, float* __restrict__ weights) {
  const int b = blockIdx.x;
  const int tid = threadIdx.x;
  float v[8];
  float mx = -INFINITY;
#pragma unroll
  for (int i = 0; i < 8; ++i) {
    v[i] = scores[b * T_ + i * 256 + tid];
    mx = fmaxf(mx, v[i]);
  }
#pragma unroll
  for (int off = 32; off > 0; off >>= 1) mx = fmaxf(mx, __shfl_down(mx, off));
  __shared__ float sm[4], ss[4];
  if ((tid & 63) == 0) sm[tid >> 6] = mx;
  __syncthreads();
  mx = fmaxf(fmaxf(sm[0], sm[1]), fmaxf(sm[2], sm[3]));
  float sum = 0.f;
#pragma unroll
  for (int i = 0; i < 8; ++i) {
    v[i] = __expf(v[i] - mx);
    sum += v[i];
  }
#pragma unroll
  for (int off = 32; off > 0; off >>= 1) sum += __shfl_down(sum, off);
  if ((tid & 63) == 0) ss[tid >> 6] = sum;
  __syncthreads();
  const float inv = 1.f / (ss[0] + ss[1] + ss[2] + ss[3]);
#pragma unroll
  for (int i = 0; i < 8; ++i) weights[b * T_ + i * 256 + tid] = v[i] * inv;
}

// ---------------- context = sum_t w * values ----------------
__global__ __launch_bounds__(256) void context_kernel(
    const float* __restrict__ values, const float* __restrict__ weights,
    float* __restrict__ context) {
  const int b = blockIdx.x;
  const int t0 = blockIdx.y * 64;
  const int tid = threadIdx.x;
  __shared__ float w[64];
  if (tid < 64) w[tid] = weights[b * T_ + t0 + tid];
  __syncthreads();
  float2 acc = make_float2(0.f, 0.f);
  const float2* vp = (const float2*)(values + (long)(b * T_ + t0) * D_) + tid;
#pragma unroll 4
  for (int t = 0; t < 64; ++t) {
    const float2 x = vp[(long)t * (D_ / 2)];
    acc.x += w[t] * x.x;
    acc.y += w[t] * x.y;
  }
  atomicAdd(context + b * D_ + tid * 2 + 0, acc.x);
  atomicAdd(context + b * D_ + tid * 2 + 1, acc.y);
}

extern "C" void kernel_launch(void* const* d_in, const int* in_sizes, int n_in,
                              void* d_out, int out_size, void* d_ws, size_t ws_size,
                              hipStream_t stream) {
  const float* values = (const float*)d_in[0];
  const float* query = (const float*)d_in[1];
  const float* W1 = (const float*)d_in[2];
  const float* b1 = (const float*)d_in[3];
  const float* W2 = (const float*)d_in[4];
  const float* b2 = (const float*)d_in[5];
  const float* V = (const float*)d_in[6];
  // d_in[7] = bV: unused — softmax is shift-invariant.

  float* out = (float*)d_out;
  float* context = out;            // [32,512]
  float* weights = out + B_ * D_;  // [32,2048]
  float* projq = (float*)d_ws;     // [32,512]   = 64KB
  float* scores = projq + B_ * U_; // [32,2048]  = 256KB
  _Float16* w1t = (_Float16*)((char*)d_ws + 65536 + 262144);  // 512KB

  const bool fast = ws_size >= (size_t)(65536 + 262144 + 524288);

  hipMemsetAsync(scores, 0, M_ * sizeof(float), stream);
  hipMemsetAsync(context, 0, B_ * D_ * sizeof(float), stream);

  projq_kernel<<<dim3(B_, U_ / 256), 256, 0, stream>>>(query, W2, b2, projq);
  if (fast) {
    prep_w1t<<<dim3(D_ / 64, U_ / 64), 256, 0, stream>>>(W1, w1t);
    score_direct_kernel<<<dim3(M_ / 128, U_ / 128), 256, 0, stream>>>(
        values, w1t, b1, projq, V, scores);
  } else {
    score_mfma_kernel<<<dim3(M_ / 128, U_ / 128), 256, 0, stream>>>(
        values, W1, b1, projq, V, scores);
  }
  softmax_kernel<<<B_, 256, 0, stream>>>(scores, weights);
  context_kernel<<<dim3(B_, T_ / 64), 256, 0, stream>>>(values, weights, context);
}

// Round 4
// 364.823 us; speedup vs baseline: 1.1213x; 1.1213x over previous
//
#include <hip/hip_runtime.h>
#include <math.h>

// Bahdanau attention, B=32, T=2048, D=512, U=512, fp32 in/out.
// Round 4: LDS-staged A (padded stride 40 f16 -> 2-way conflicts = free),
// B fragments direct-from-global (w1t f16 [u][k], L2-resident) with register
// prefetch, global loads hoisted one K-iter ahead of the 2-barrier loop.
// Memsets folded into projq/softmax; context uses float4 + 2-group combine.

#define B_ 32
#define T_ 2048
#define D_ 512
#define U_ 512
#define M_ (B_ * T_)

typedef _Float16 half8 __attribute__((ext_vector_type(8)));
typedef float floatx4 __attribute__((ext_vector_type(4)));

__device__ __forceinline__ float fast_tanh(float x) {
  x = fminf(fmaxf(x, -20.f), 20.f);
  const float e = __expf(2.f * x);
  return 1.f - 2.f / (e + 1.f);
}

// ---------------- proj_q = query @ W2 + b2  (+ zero scores) ----------------
__global__ __launch_bounds__(256) void projq_kernel(
    const float* __restrict__ query, const float* __restrict__ W2,
    const float* __restrict__ b2, float* __restrict__ projq,
    float* __restrict__ scores) {
  // zero scores: grid (32,2) x 256 = 16384 threads, scores = 16384 float4
  const int gid = (blockIdx.x * gridDim.y + blockIdx.y) * 256 + threadIdx.x;
  ((float4*)scores)[gid] = make_float4(0.f, 0.f, 0.f, 0.f);

  const int b = blockIdx.x;
  const int u = blockIdx.y * 256 + threadIdx.x;
  __shared__ float q[D_];
  for (int d = threadIdx.x; d < D_; d += 256) q[d] = query[b * D_ + d];
  __syncthreads();
  float acc = 0.f;
#pragma unroll 8
  for (int d = 0; d < D_; ++d) acc += q[d] * W2[d * U_ + u];
  projq[b * U_ + u] = acc + b2[u];
}

// ---------------- W1 [k][u] -> w1t [u][k] f16 ----------------
__global__ __launch_bounds__(256) void prep_w1t(
    const float* __restrict__ W1, _Float16* __restrict__ w1t) {
  __shared__ float t[64][65];
  const int k0 = blockIdx.x * 64, u0 = blockIdx.y * 64;
  const int lu = threadIdx.x & 63;
  const int g = threadIdx.x >> 6;
#pragma unroll
  for (int i = 0; i < 16; ++i) {
    const int row = g * 16 + i;
    t[row][lu] = W1[(long)(k0 + row) * U_ + u0 + lu];
  }
  __syncthreads();
#pragma unroll
  for (int i = 0; i < 16; ++i) {
    const int row = g * 16 + i;
    w1t[(long)(u0 + row) * D_ + k0 + lu] = (_Float16)t[lu][row];
  }
}

// ---------------- scores: pipelined f16 MFMA GEMM + tanh/V epilogue -------
// Tile 128(M) x 128(U), BK=32, 4 waves 2x2, wave = 64x64 via 4x4 16x16x32.
// A: values fp32 -> cvt -> LDS [128][40] (pad => 2-way bank = free).
// B: direct global half8 from w1t (L2-resident), register double-buffered.
// Frag layouts (verified rounds 2/3): A[m=lane&15][k=(lane>>4)*8+j],
// B[k=(lane>>4)*8+j][n=lane&15], C[row=(lane>>4)*4+reg][col=lane&15].
__global__ __launch_bounds__(256) void score_lds_kernel(
    const float* __restrict__ values, const _Float16* __restrict__ w1t,
    const float* __restrict__ b1, const float* __restrict__ projq,
    const float* __restrict__ V, float* __restrict__ scores) {
  const int m0 = blockIdx.x * 128;
  const int u0 = blockIdx.y * 128;
  const int b = blockIdx.x >> 4;  // 2048/128 = 16 row-blocks per batch
  const int tid = threadIdx.x;
  const int lane = tid & 63;
  const int w = tid >> 6;
  const int wm = (w & 1) * 64;
  const int wn = (w >> 1) * 64;
  const int ln = lane & 15;
  const int lq = lane >> 4;

  __shared__ alignas(16) _Float16 As[128 * 40];  // [m][k], stride 40

  // A staging map: thread -> (row srow, k-half skoff), 16 fp32 each
  const int srow = tid >> 1;
  const int skoff = (tid & 1) * 16;
  const float* aptr = values + (long)(m0 + srow) * D_ + skoff;
  _Float16* awr = &As[srow * 40 + skoff];

  const _Float16* bBase = w1t + (long)(u0 + wn + ln) * D_ + lq * 8;

  floatx4 acc[4][4] = {};
  float4 ar[4];
  half8 bf[4], bfn[4];

  // prologue: k0 = 0 loads
  ar[0] = *(const float4*)(aptr + 0);
  ar[1] = *(const float4*)(aptr + 4);
  ar[2] = *(const float4*)(aptr + 8);
  ar[3] = *(const float4*)(aptr + 12);
#pragma unroll
  for (int ni = 0; ni < 4; ++ni)
    bf[ni] = *(const half8*)(bBase + (long)ni * 16 * D_);
  {
    half8 h0 = {(_Float16)ar[0].x, (_Float16)ar[0].y, (_Float16)ar[0].z, (_Float16)ar[0].w,
                (_Float16)ar[1].x, (_Float16)ar[1].y, (_Float16)ar[1].z, (_Float16)ar[1].w};
    half8 h1 = {(_Float16)ar[2].x, (_Float16)ar[2].y, (_Float16)ar[2].z, (_Float16)ar[2].w,
                (_Float16)ar[3].x, (_Float16)ar[3].y, (_Float16)ar[3].z, (_Float16)ar[3].w};
    *(half8*)awr = h0;
    *(half8*)(awr + 8) = h1;
  }

  for (int k0 = 0; k0 < D_; k0 += 32) {
    const bool more = (k0 + 32) < D_;
    if (more) {  // issue next iteration's global loads NOW
      ar[0] = *(const float4*)(aptr + k0 + 32);
      ar[1] = *(const float4*)(aptr + k0 + 36);
      ar[2] = *(const float4*)(aptr + k0 + 40);
      ar[3] = *(const float4*)(aptr + k0 + 44);
#pragma unroll
      for (int ni = 0; ni < 4; ++ni)
        bfn[ni] = *(const half8*)(bBase + (long)ni * 16 * D_ + k0 + 32);
    }
    __syncthreads();  // A-tile writes visible
    half8 af[4];
#pragma unroll
    for (int i = 0; i < 4; ++i)
      af[i] = *(const half8*)&As[(wm + i * 16 + ln) * 40 + lq * 8];
#pragma unroll
    for (int mi = 0; mi < 4; ++mi)
#pragma unroll
      for (int ni = 0; ni < 4; ++ni)
        acc[mi][ni] = __builtin_amdgcn_mfma_f32_16x16x32_f16(
            af[mi], bf[ni], acc[mi][ni], 0, 0, 0);
    __syncthreads();  // A-tile reads done
    if (more) {
      half8 h0 = {(_Float16)ar[0].x, (_Float16)ar[0].y, (_Float16)ar[0].z, (_Float16)ar[0].w,
                  (_Float16)ar[1].x, (_Float16)ar[1].y, (_Float16)ar[1].z, (_Float16)ar[1].w};
      half8 h1 = {(_Float16)ar[2].x, (_Float16)ar[2].y, (_Float16)ar[2].z, (_Float16)ar[2].w,
                  (_Float16)ar[3].x, (_Float16)ar[3].y, (_Float16)ar[3].z, (_Float16)ar[3].w};
      *(half8*)awr = h0;
      *(half8*)(awr + 8) = h1;
#pragma unroll
      for (int ni = 0; ni < 4; ++ni) bf[ni] = bfn[ni];
    }
  }

  // Epilogue: s[row] += sum_col tanh(c + b1[u] + projq[b,u]) * V[u]
  float pre[4], vv[4];
#pragma unroll
  for (int ni = 0; ni < 4; ++ni) {
    const int u = u0 + wn + ni * 16 + ln;
    pre[ni] = b1[u] + projq[b * U_ + u];
    vv[ni] = V[u];
  }
#pragma unroll
  for (int mi = 0; mi < 4; ++mi) {
#pragma unroll
    for (int r = 0; r < 4; ++r) {
      float t = 0.f;
#pragma unroll
      for (int ni = 0; ni < 4; ++ni)
        t += fast_tanh(acc[mi][ni][r] + pre[ni]) * vv[ni];
      t += __shfl_xor(t, 1);
      t += __shfl_xor(t, 2);
      t += __shfl_xor(t, 4);
      t += __shfl_xor(t, 8);
      if (ln == mi * 4 + r)  // one atomic per lane
        atomicAdd(scores + m0 + wm + mi * 16 + lq * 4 + r, t);
    }
  }
}

// ---------------- round-2 LDS kernel: fallback if ws too small ------------
__global__ __launch_bounds__(256) void score_mfma_kernel(
    const float* __restrict__ values, const float* __restrict__ W1,
    const float* __restrict__ b1, const float* __restrict__ projq,
    const float* __restrict__ V, float* __restrict__ scores) {
  const int m0 = blockIdx.x * 128;
  const int u0 = blockIdx.y * 128;
  const int b = blockIdx.x >> 4;
  const int tid = threadIdx.x;
  __shared__ alignas(16) _Float16 As[128 * 32];
  __shared__ alignas(16) _Float16 Bs[128 * 32];
  const int lane = tid & 63;
  const int w = tid >> 6;
  const int wm = (w & 1) * 64;
  const int wn = (w >> 1) * 64;
  const int ln = lane & 15;
  const int lq = lane >> 4;
  floatx4 acc[4][4] = {};
  const int srow = tid >> 1;
  const int skoff = (tid & 1) * 16;
  const float* aptr = values + (long)(m0 + srow) * D_ + skoff;
  const float* bptr = W1 + u0 + srow;
  for (int k0 = 0; k0 < D_; k0 += 32) {
    const float4 a0 = *(const float4*)(aptr + k0);
    const float4 a1 = *(const float4*)(aptr + k0 + 4);
    const float4 a2 = *(const float4*)(aptr + k0 + 8);
    const float4 a3 = *(const float4*)(aptr + k0 + 12);
    half8 ha0 = {(_Float16)a0.x, (_Float16)a0.y, (_Float16)a0.z, (_Float16)a0.w,
                 (_Float16)a1.x, (_Float16)a1.y, (_Float16)a1.z, (_Float16)a1.w};
    half8 ha1 = {(_Float16)a2.x, (_Float16)a2.y, (_Float16)a2.z, (_Float16)a2.w,
                 (_Float16)a3.x, (_Float16)a3.y, (_Float16)a3.z, (_Float16)a3.w};
    float bt[16];
#pragma unroll
    for (int kk = 0; kk < 16; ++kk)
      bt[kk] = bptr[(long)(k0 + skoff + kk) * U_];
    half8 hb0 = {(_Float16)bt[0], (_Float16)bt[1], (_Float16)bt[2], (_Float16)bt[3],
                 (_Float16)bt[4], (_Float16)bt[5], (_Float16)bt[6], (_Float16)bt[7]};
    half8 hb1 = {(_Float16)bt[8], (_Float16)bt[9], (_Float16)bt[10], (_Float16)bt[11],
                 (_Float16)bt[12], (_Float16)bt[13], (_Float16)bt[14], (_Float16)bt[15]};
    *(half8*)&As[srow * 32 + skoff] = ha0;
    *(half8*)&As[srow * 32 + skoff + 8] = ha1;
    *(half8*)&Bs[srow * 32 + skoff] = hb0;
    *(half8*)&Bs[srow * 32 + skoff + 8] = hb1;
    __syncthreads();
    half8 af[4], bf[4];
#pragma unroll
    for (int i = 0; i < 4; ++i) {
      af[i] = *(const half8*)&As[(wm + i * 16 + ln) * 32 + lq * 8];
      bf[i] = *(const half8*)&Bs[(wn + i * 16 + ln) * 32 + lq * 8];
    }
#pragma unroll
    for (int mi = 0; mi < 4; ++mi)
#pragma unroll
      for (int ni = 0; ni < 4; ++ni)
        acc[mi][ni] = __builtin_amdgcn_mfma_f32_16x16x32_f16(
            af[mi], bf[ni], acc[mi][ni], 0, 0, 0);
    __syncthreads();
  }
  float pre[4], vv[4];
#pragma unroll
  for (int ni = 0; ni < 4; ++ni) {
    const int u = u0 + wn + ni * 16 + ln;
    pre[ni] = b1[u] + projq[b * U_ + u];
    vv[ni] = V[u];
  }
#pragma unroll
  for (int mi = 0; mi < 4; ++mi) {
#pragma unroll
    for (int r = 0; r < 4; ++r) {
      float t = 0.f;
#pragma unroll
      for (int ni = 0; ni < 4; ++ni)
        t += fast_tanh(acc[mi][ni][r] + pre[ni]) * vv[ni];
      t += __shfl_xor(t, 1);
      t += __shfl_xor(t, 2);
      t += __shfl_xor(t, 4);
      t += __shfl_xor(t, 8);
      if (ln == mi * 4 + r)
        atomicAdd(scores + m0 + wm + mi * 16 + lq * 4 + r, t);
    }
  }
}

// ---------------- softmax over T per batch (+ zero context) ----------------
__global__ __launch_bounds__(256) void softmax_kernel(
    const float* __restrict__ scores, float* __restrict__ weights,
    float* __restrict__ context) {
  // zero context: 32 blocks x 256 threads = 8192 = context float2 count
  ((float2*)context)[blockIdx.x * 256 + threadIdx.x] = make_float2(0.f, 0.f);

  const int b = blockIdx.x;
  const int tid = threadIdx.x;
  float v[8];
  float mx = -INFINITY;
#pragma unroll
  for (int i = 0; i < 8; ++i) {
    v[i] = scores[b * T_ + i * 256 + tid];
    mx = fmaxf(mx, v[i]);
  }
#pragma unroll
  for (int off = 32; off > 0; off >>= 1) mx = fmaxf(mx, __shfl_down(mx, off));
  __shared__ float sm[4], ss[4];
  if ((tid & 63) == 0) sm[tid >> 6] = mx;
  __syncthreads();
  mx = fmaxf(fmaxf(sm[0], sm[1]), fmaxf(sm[2], sm[3]));
  float sum = 0.f;
#pragma unroll
  for (int i = 0; i < 8; ++i) {
    v[i] = __expf(v[i] - mx);
    sum += v[i];
  }
#pragma unroll
  for (int off = 32; off > 0; off >>= 1) sum += __shfl_down(sum, off);
  if ((tid & 63) == 0) ss[tid >> 6] = sum;
  __syncthreads();
  const float inv = 1.f / (ss[0] + ss[1] + ss[2] + ss[3]);
#pragma unroll
  for (int i = 0; i < 8; ++i) weights[b * T_ + i * 256 + tid] = v[i] * inv;
}

// ---------------- context = sum_t w * values ----------------
// 64-row tiles, float4 loads, 2 row-groups combined in LDS, 1 atomic set.
__global__ __launch_bounds__(256) void context_kernel(
    const float* __restrict__ values, const float* __restrict__ weights,
    float* __restrict__ context) {
  const int b = blockIdx.x;
  const int t0 = blockIdx.y * 64;
  const int tid = threadIdx.x;
  const int g = tid >> 7;      // row-parity group
  const int dx = tid & 127;    // float4 index over D
  __shared__ float wsh[64];
  __shared__ float4 part[128];
  if (tid < 64) wsh[tid] = weights[b * T_ + t0 + tid];
  __syncthreads();
  float4 acc = make_float4(0.f, 0.f, 0.f, 0.f);
  const float4* vp = (const float4*)(values + (long)(b * T_ + t0 + g) * D_) + dx;
#pragma unroll 4
  for (int t = 0; t < 32; ++t) {
    const float4 x = vp[(long)(2 * t) * (D_ / 4)];
    const float ww = wsh[2 * t + g];
    acc.x += ww * x.x; acc.y += ww * x.y; acc.z += ww * x.z; acc.w += ww * x.w;
  }
  if (g == 0) part[dx] = acc;
  __syncthreads();
  if (g == 1) {
    const float4 p = part[dx];
    atomicAdd(&context[b * D_ + dx * 4 + 0], acc.x + p.x);
    atomicAdd(&context[b * D_ + dx * 4 + 1], acc.y + p.y);
    atomicAdd(&context[b * D_ + dx * 4 + 2], acc.z + p.z);
    atomicAdd(&context[b * D_ + dx * 4 + 3], acc.w + p.w);
  }
}

extern "C" void kernel_launch(void* const* d_in, const int* in_sizes, int n_in,
                              void* d_out, int out_size, void* d_ws, size_t ws_size,
                              hipStream_t stream) {
  const float* values = (const float*)d_in[0];
  const float* query = (const float*)d_in[1];
  const float* W1 = (const float*)d_in[2];
  const float* b1 = (const float*)d_in[3];
  const float* W2 = (const float*)d_in[4];
  const float* b2 = (const float*)d_in[5];
  const float* V = (const float*)d_in[6];
  // d_in[7] = bV: unused — softmax is shift-invariant.

  float* out = (float*)d_out;
  float* context = out;            // [32,512]
  float* weights = out + B_ * D_;  // [32,2048]
  float* projq = (float*)d_ws;     // [32,512]   64KB
  float* scores = projq + B_ * U_; // [32,2048]  256KB
  _Float16* w1t = (_Float16*)((char*)d_ws + 65536 + 262144);  // 512KB

  const bool fast = ws_size >= (size_t)(65536 + 262144 + 524288);

  projq_kernel<<<dim3(B_, U_ / 256), 256, 0, stream>>>(query, W2, b2, projq, scores);
  if (fast) {
    prep_w1t<<<dim3(D_ / 64, U_ / 64), 256, 0, stream>>>(W1, w1t);
    score_lds_kernel<<<dim3(M_ / 128, U_ / 128), 256, 0, stream>>>(
        values, w1t, b1, projq, V, scores);
  } else {
    score_mfma_kernel<<<dim3(M_ / 128, U_ / 128), 256, 0, stream>>>(
        values, W1, b1, projq, V, scores);
  }
  softmax_kernel<<<B_, 256, 0, stream>>>(scores, weights, context);
  context_kernel<<<dim3(B_, T_ / 64), 256, 0, stream>>>(values, weights, context);
}